// Round 2
// baseline (99.275 us; speedup 1.0000x reference)
//
#include <hip/hip_runtime.h>
#include <cstdint>

// WealthRNN: per-element nonlinear scan, S=1024, B=16384. 256 blocks x 64 thr
// = 1 wave/CU (structural). Latency-bound before (8 KiB in flight -> 1 TB/s).
// Now: 4-step groups DMA'd via global_load_lds_dwordx4 into a 32-slot LDS
// ring, depth-20 prefetch (40 KiB in flight/CU), manual counted vmcnt
// (3 VMEM ops per steady iter: 2 DMA + 1 dwordx4 store), one-group-ahead
// LDS->reg read, output transpose through LDS for dwordx4 stores.

#define S_LEN 1024
#define B_LEN 16384
#define NG    255      // 4-step groups covering steps 1..1020
#define D     20       // prefetch depth in groups
#define NSLOT 32       // LDS ring slots (>= D+1, power of 2)

// vmcnt accounting (in-order retirement):
//  warmup wait for group g+1 (prologue-issued): min newer ops = 2D-2 = 38
//  steady wait for group g+1: exactly 3 VMEM/iter, worst-case order = 3D-3 = 57
#define WAIT_WARM   asm volatile("s_waitcnt vmcnt(38)" ::: "memory")
#define WAIT_STEADY asm volatile("s_waitcnt vmcnt(57)" ::: "memory")

__device__ __forceinline__ void dma16(const float* g, float* l) {
    __builtin_amdgcn_global_load_lds(
        (const __attribute__((address_space(1))) void*)g,
        (__attribute__((address_space(3))) void*)l,
        16, 0, 0);
}

__device__ __forceinline__ float step_fn(float h, float x, float r,
                                         float win, float wh,
                                         float c1, float c2, float c3,
                                         float wf1, float wf2) {
    float inv   = __builtin_amdgcn_rcpf(fmaf(h, r, 1.0f)); // 1/(1+h*r)
    float h_adj = fmaf(h, r, h) * inv;                      // h*(1+r)/(1+h*r)
    float ingate = fmaf(wh, h_adj, fmaf(x, win, c1));
    float t  = fmaxf(ingate, 0.0f);
    float g2 = fmaf(wf1, t, c2);
    float t2 = fmaxf(g2, 0.0f);
    return fmaf(wf2, t2, c3);
}

__global__ __launch_bounds__(64) void wealth_rnn_kernel(
    const float* __restrict__ inputs,    // [S, B]
    const float* __restrict__ returns,   // [S-1, B]
    const float* __restrict__ target,
    const float* __restrict__ w_in_p,
    const float* __restrict__ w_h_p,
    const float* __restrict__ b_h_p,
    const float* __restrict__ w_fc1_p,
    const float* __restrict__ w_fc2_p,
    float* __restrict__ out)             // [S*B] then [B] hT
{
    // ring[slot][0]=x tile [4 steps][64 lanes], ring[slot][1]=r tile
    __shared__ alignas(16) float ring[NSLOT][2][4][64];   // 64 KiB
    __shared__ alignas(16) float outb[2][4][64];          // 2 KiB

    const int lane = threadIdx.x;
    const int b0   = blockIdx.x * 64;
    const int b    = b0 + lane;
    const int lr   = lane >> 4;          // row (step-within-group) this lane DMAs/stores
    const int lc   = (lane & 15) * 4;    // col (batch offset) this lane DMAs/stores

    const float pi_bar = target[0];
    const float win = w_in_p[0];
    const float wh  = w_h_p[0];
    const float bh  = b_h_p[0];
    const float wf1 = w_fc1_p[0];
    const float wf2 = w_fc2_p[0];
    const float c1 = bh - pi_bar;
    const float c2 = 2.0f * bh;
    const float c3 = pi_bar + bh;

    // step 0
    float h = inputs[b];
    out[b] = h;

    // per-lane DMA source pointers: group g covers x rows 4g+1..4g+4,
    // r rows 4g..4g+3; lane handles row +lr, cols [b0+lc, b0+lc+4)
    const size_t gstep = (size_t)4 * B_LEN;
    const float* gx = inputs  + (size_t)(1 + lr) * B_LEN + b0 + lc;
    const float* gr = returns + (size_t)lr       * B_LEN + b0 + lc;

    // prologue: DMA groups 0..D-1 (DMA-DMA order preserved: mutual LDS may-alias)
#pragma unroll
    for (int j = 0; j < D; ++j) {
        dma16(gx + (size_t)j * gstep, &ring[j][0][0][0]);
        dma16(gr + (size_t)j * gstep, &ring[j][1][0][0]);
    }

    // pre-read group 0 into regs
    WAIT_WARM;
    __builtin_amdgcn_sched_barrier(0);
    float xc[4], rc[4], xn[4], rn[4];
#pragma unroll
    for (int k = 0; k < 4; ++k) { xc[k] = ring[0][0][k][lane]; rc[k] = ring[0][1][k][lane]; }

    const float* gxi = gx + (size_t)D * gstep;   // DMA src for group g+D
    const float* gri = gr + (size_t)D * gstep;
    float* gout = out + (size_t)(1 + lr) * B_LEN + b0 + lc; // store dst, group 0

    // ---- warmup: g in [0, D) ----
    for (int g = 0; g < D; ++g) {
        const int si = (g + D) & (NSLOT - 1);
        dma16(gxi, &ring[si][0][0][0]);
        dma16(gri, &ring[si][1][0][0]);
        gxi += gstep; gri += gstep;
        if (g >= 1) {  // deferred store of group g-1 (written to outb last iter)
            float4 ov = *(const float4*)&outb[(g - 1) & 1][lr][lc];
            *(float4*)gout = ov;
            gout += gstep;
        }
        WAIT_WARM;
        __builtin_amdgcn_sched_barrier(0);
        const int s2 = (g + 1) & (NSLOT - 1);
#pragma unroll
        for (int k = 0; k < 4; ++k) { xn[k] = ring[s2][0][k][lane]; rn[k] = ring[s2][1][k][lane]; }
#pragma unroll
        for (int k = 0; k < 4; ++k) {
            h = step_fn(h, xc[k], rc[k], win, wh, c1, c2, c3, wf1, wf2);
            outb[g & 1][k][lane] = h;
        }
#pragma unroll
        for (int k = 0; k < 4; ++k) { xc[k] = xn[k]; rc[k] = rn[k]; }
    }

    // ---- steady: g in [D, NG-D) ----
    for (int g = D; g < NG - D; ++g) {
        const int si = (g + D) & (NSLOT - 1);
        dma16(gxi, &ring[si][0][0][0]);
        dma16(gri, &ring[si][1][0][0]);
        gxi += gstep; gri += gstep;
        {
            float4 ov = *(const float4*)&outb[(g - 1) & 1][lr][lc];
            *(float4*)gout = ov;
            gout += gstep;
        }
        WAIT_STEADY;
        __builtin_amdgcn_sched_barrier(0);
        const int s2 = (g + 1) & (NSLOT - 1);
#pragma unroll
        for (int k = 0; k < 4; ++k) { xn[k] = ring[s2][0][k][lane]; rn[k] = ring[s2][1][k][lane]; }
#pragma unroll
        for (int k = 0; k < 4; ++k) {
            h = step_fn(h, xc[k], rc[k], win, wh, c1, c2, c3, wf1, wf2);
            outb[g & 1][k][lane] = h;
        }
#pragma unroll
        for (int k = 0; k < 4; ++k) { xc[k] = xn[k]; rc[k] = rn[k]; }
    }

    // ---- drain: everything issued; wait once, consume rest ----
    asm volatile("s_waitcnt vmcnt(0)" ::: "memory");
    __builtin_amdgcn_sched_barrier(0);
    for (int g = NG - D; g < NG; ++g) {
        {
            float4 ov = *(const float4*)&outb[(g - 1) & 1][lr][lc];
            *(float4*)gout = ov;
            gout += gstep;
        }
        if (g + 1 < NG) {
            const int s2 = (g + 1) & (NSLOT - 1);
#pragma unroll
            for (int k = 0; k < 4; ++k) { xn[k] = ring[s2][0][k][lane]; rn[k] = ring[s2][1][k][lane]; }
        }
#pragma unroll
        for (int k = 0; k < 4; ++k) {
            h = step_fn(h, xc[k], rc[k], win, wh, c1, c2, c3, wf1, wf2);
            outb[g & 1][k][lane] = h;
        }
#pragma unroll
        for (int k = 0; k < 4; ++k) { xc[k] = xn[k]; rc[k] = rn[k]; }
    }

    // store last group (NG-1)
    {
        float4 ov = *(const float4*)&outb[(NG - 1) & 1][lr][lc];
        *(float4*)gout = ov;
    }

    // tail steps 1021..1023 (scalar)
#pragma unroll
    for (int s = 4 * NG + 1; s < S_LEN; ++s) {
        const float x = inputs[(size_t)s * B_LEN + b];
        const float r = returns[(size_t)(s - 1) * B_LEN + b];
        h = step_fn(h, x, r, win, wh, c1, c2, c3, wf1, wf2);
        out[(size_t)s * B_LEN + b] = h;
    }

    // hT
    out[(size_t)S_LEN * B_LEN + b] = h;
}

extern "C" void kernel_launch(void* const* d_in, const int* in_sizes, int n_in,
                              void* d_out, int out_size, void* d_ws, size_t ws_size,
                              hipStream_t stream) {
    const float* inputs  = (const float*)d_in[0];
    const float* returns = (const float*)d_in[1];
    const float* target  = (const float*)d_in[2];
    const float* w_in    = (const float*)d_in[3];
    const float* w_h     = (const float*)d_in[4];
    const float* b_h     = (const float*)d_in[5];
    const float* w_fc1   = (const float*)d_in[6];
    const float* w_fc2   = (const float*)d_in[7];
    float* out = (float*)d_out;

    dim3 grid(B_LEN / 64);
    dim3 block(64);
    hipLaunchKernelGGL(wealth_rnn_kernel, grid, block, 0, stream,
                       inputs, returns, target, w_in, w_h, b_h, w_fc1, w_fc2, out);
}

// Round 4
// 61.132 us; speedup vs baseline: 1.6239x; 1.6239x over previous
//
#include <hip/hip_runtime.h>
#include <cstdint>

// WealthRNN v4: producer/consumer 2-wave design.
//  wave0: DMA (global_load_lds, 2 ops/group, depth D=24 groups) -> asm ds_read
//         -> 4-step recurrence -> ds_write outputs to LDS double buffer.
//         vmcnt stream = DMAs ONLY -> exact counted waits (vmcnt(46)).
//  wave1: per group: s_barrier, vmcnt(0) (store-src protect), ds_read_b128,
//         buffer_store_dwordx4. vmcnt stream = stores only.
// No async-written long-lived VGPRs (R2's failure class). No plain LDS reads
// of DMA'd data (R1's compiler-drain failure class). Raw s_barrier only.

#define S_LEN 1024
#define B_LEN 16384
#define NG    255      // 4-step groups, steps 1..1020
#define D     24       // DMA prefetch depth (groups); wait N = 2D-2 = 46
#define NSLOT 32
#define GSTEP ((size_t)4 * B_LEN)

typedef uint32_t u32x4 __attribute__((ext_vector_type(4)));
typedef float    f32x4 __attribute__((ext_vector_type(4)));

static_assert(NG - D == 231, "loop split");

__device__ __forceinline__ u32x4 make_srsrc(const void* p) {
    u32x4 r;
    uint64_t a = (uint64_t)p;
    r.x = (uint32_t)a;
    r.y = (uint32_t)(a >> 32);   // base hi, stride=0
    r.z = 0xFFFFFFFFu;           // bounds check disabled
    r.w = 0x00020000u;           // raw dword descriptor
    return r;
}

#define WAITV(N) do { \
    asm volatile("s_waitcnt vmcnt(%0)" :: "n"(N)); \
    __builtin_amdgcn_sched_barrier(0); } while (0)

#define LGKM0 do { \
    asm volatile("s_waitcnt lgkmcnt(0)"); \
    __builtin_amdgcn_sched_barrier(0); } while (0)

__device__ __forceinline__ void dma16(const float* g, float* l) {
    __builtin_amdgcn_global_load_lds(
        (const __attribute__((address_space(1))) void*)g,
        (__attribute__((address_space(3))) void*)l, 16, 0, 0);
}

// read one group tile (x[0..3], r[0..3]) for this lane's column from slot @ra
#define DSR8(xa, ra_, ca_) do { \
    asm volatile("ds_read_b32 %0, %1 offset:0"    : "=v"(xa[0]) : "v"(ra_)); \
    asm volatile("ds_read_b32 %0, %1 offset:256"  : "=v"(xa[1]) : "v"(ra_)); \
    asm volatile("ds_read_b32 %0, %1 offset:512"  : "=v"(xa[2]) : "v"(ra_)); \
    asm volatile("ds_read_b32 %0, %1 offset:768"  : "=v"(xa[3]) : "v"(ra_)); \
    asm volatile("ds_read_b32 %0, %1 offset:1024" : "=v"(ca_[0]) : "v"(ra_)); \
    asm volatile("ds_read_b32 %0, %1 offset:1280" : "=v"(ca_[1]) : "v"(ra_)); \
    asm volatile("ds_read_b32 %0, %1 offset:1536" : "=v"(ca_[2]) : "v"(ra_)); \
    asm volatile("ds_read_b32 %0, %1 offset:1792" : "=v"(ca_[3]) : "v"(ra_)); \
} while (0)

__device__ __forceinline__ float step_fn(float h, float x, float r,
                                         float win, float wh,
                                         float c1, float c2, float c3,
                                         float wf1, float wf2) {
    float inv   = __builtin_amdgcn_rcpf(fmaf(h, r, 1.0f)); // 1/(1+h*r)
    float h_adj = fmaf(h, r, h) * inv;                      // h*(1+r)/(1+h*r)
    float ingate = fmaf(wh, h_adj, fmaf(x, win, c1));
    float t  = fmaxf(ingate, 0.0f);
    float g2 = fmaf(wf1, t, c2);
    float t2 = fmaxf(g2, 0.0f);
    return fmaf(wf2, t2, c3);
}

__global__ __launch_bounds__(128) void wealth_rnn_kernel(
    const float* __restrict__ inputs,    // [S, B]
    const float* __restrict__ returns,   // [S-1, B]
    const float* __restrict__ target,
    const float* __restrict__ w_in_p,
    const float* __restrict__ w_h_p,
    const float* __restrict__ b_h_p,
    const float* __restrict__ w_fc1_p,
    const float* __restrict__ w_fc2_p,
    float* __restrict__ out)             // [S*B] then [B] hT
{
    __shared__ float ring[NSLOT][2][4][64];   // 64 KiB x/r staging ring
    __shared__ float outb[2][4][64];          // 2 KiB output double buffer

    const int tid  = threadIdx.x;
    const int lane = tid & 63;
    const int wid  = tid >> 6;
    const int b0   = blockIdx.x * 64;

    if (wid == 0) {
        // ======================= producer / compute wave =====================
        const int b = b0 + lane;
        const float pi_bar = target[0];
        const float win = w_in_p[0];
        const float wh  = w_h_p[0];
        const float bh  = b_h_p[0];
        const float wf1 = w_fc1_p[0];
        const float wf2 = w_fc2_p[0];
        const float c1 = bh - pi_bar;
        const float c2 = 2.0f * bh;
        const float c3 = pi_bar + bh;

        // step 0: h = inputs[0]; store row 0 via asm (keeps compiler VMEM out
        // of the counted region; one extra old op only tightens later waits)
        float h = inputs[b];
        u32x4 ro = make_srsrc(out);
        const uint32_t voff = (uint32_t)b * 4u;
        const uint32_t so0 = 0u;
        asm volatile("buffer_store_dword %0, %1, %2, %3 offen"
                     :: "v"(h), "v"(voff), "s"(ro), "s"(so0));

        const int lr = lane >> 4;
        const int lc = (lane & 15) * 4;
        const float* gxi = inputs  + (size_t)(1 + lr) * B_LEN + b0 + lc;
        const float* gri = returns + (size_t)lr       * B_LEN + b0 + lc;

        asm volatile("" ::: "memory");  // fence: pin entry mem-ops above region

        // prologue: DMA groups 0..D-1 (2D = 48 vm ops)
#pragma unroll
        for (int j = 0; j < D; ++j) {
            dma16(gxi, &ring[j][0][0][0]);
            dma16(gri, &ring[j][1][0][0]);
            gxi += GSTEP; gri += GSTEP;
        }

        const uint32_t ring_a = (uint32_t)(uintptr_t)&ring[0][0][0][0];
        const uint32_t outb_a = (uint32_t)(uintptr_t)&outb[0][0][0];
        const uint32_t rbase = ring_a + (uint32_t)lane * 4u;
        const uint32_t wbase = outb_a + (uint32_t)lane * 4u;

        float xc[4], rc[4], xn[4], rn[4];

        WAITV(2 * D - 2);            // retire DMA(0) (+ any older entry ops)
        {
            uint32_t ra0 = rbase;    // slot 0
            DSR8(xc, ra0, rc);
        }
        LGKM0;

        // main loop g = 0..230: issue DMA(g+D); wait through DMA(g+1);
        // prefetch slot g+1 LDS->reg; compute group g; publish to wave1.
        for (int g = 0; g < NG - D; ++g) {
            dma16(gxi, &ring[(g + D) & (NSLOT - 1)][0][0][0]);
            dma16(gri, &ring[(g + D) & (NSLOT - 1)][1][0][0]);
            gxi += GSTEP; gri += GSTEP;
            WAITV(2 * D - 2);
            uint32_t ra = rbase + (uint32_t)(((g + 1) & (NSLOT - 1)) * 2048);
            DSR8(xn, ra, rn);
            uint32_t wa = wbase + (uint32_t)((g & 1) * 1024);
            h = step_fn(h, xc[0], rc[0], win, wh, c1, c2, c3, wf1, wf2);
            asm volatile("ds_write_b32 %0, %1 offset:0"   :: "v"(wa), "v"(h));
            h = step_fn(h, xc[1], rc[1], win, wh, c1, c2, c3, wf1, wf2);
            asm volatile("ds_write_b32 %0, %1 offset:256" :: "v"(wa), "v"(h));
            h = step_fn(h, xc[2], rc[2], win, wh, c1, c2, c3, wf1, wf2);
            asm volatile("ds_write_b32 %0, %1 offset:512" :: "v"(wa), "v"(h));
            h = step_fn(h, xc[3], rc[3], win, wh, c1, c2, c3, wf1, wf2);
            asm volatile("ds_write_b32 %0, %1 offset:768" :: "v"(wa), "v"(h));
            LGKM0;                         // xn/rn arrived; out-writes flushed
            __builtin_amdgcn_s_barrier();  // publish group g to wave1
#pragma unroll
            for (int k = 0; k < 4; ++k) { xc[k] = xn[k]; rc[k] = rn[k]; }
        }

        // all DMAs issued (groups 0..254); drain once, then LDS-only tail
        WAITV(0);
        for (int g = NG - D; g < NG - 1; ++g) {   // 231..253
            uint32_t ra = rbase + (uint32_t)(((g + 1) & (NSLOT - 1)) * 2048);
            DSR8(xn, ra, rn);
            uint32_t wa = wbase + (uint32_t)((g & 1) * 1024);
            h = step_fn(h, xc[0], rc[0], win, wh, c1, c2, c3, wf1, wf2);
            asm volatile("ds_write_b32 %0, %1 offset:0"   :: "v"(wa), "v"(h));
            h = step_fn(h, xc[1], rc[1], win, wh, c1, c2, c3, wf1, wf2);
            asm volatile("ds_write_b32 %0, %1 offset:256" :: "v"(wa), "v"(h));
            h = step_fn(h, xc[2], rc[2], win, wh, c1, c2, c3, wf1, wf2);
            asm volatile("ds_write_b32 %0, %1 offset:512" :: "v"(wa), "v"(h));
            h = step_fn(h, xc[3], rc[3], win, wh, c1, c2, c3, wf1, wf2);
            asm volatile("ds_write_b32 %0, %1 offset:768" :: "v"(wa), "v"(h));
            LGKM0;
            __builtin_amdgcn_s_barrier();
#pragma unroll
            for (int k = 0; k < 4; ++k) { xc[k] = xn[k]; rc[k] = rn[k]; }
        }
        {   // final group g = 254 (slot 254&1 = 0), no prefetch
            uint32_t wa = wbase + (uint32_t)(((NG - 1) & 1) * 1024);
            h = step_fn(h, xc[0], rc[0], win, wh, c1, c2, c3, wf1, wf2);
            asm volatile("ds_write_b32 %0, %1 offset:0"   :: "v"(wa), "v"(h));
            h = step_fn(h, xc[1], rc[1], win, wh, c1, c2, c3, wf1, wf2);
            asm volatile("ds_write_b32 %0, %1 offset:256" :: "v"(wa), "v"(h));
            h = step_fn(h, xc[2], rc[2], win, wh, c1, c2, c3, wf1, wf2);
            asm volatile("ds_write_b32 %0, %1 offset:512" :: "v"(wa), "v"(h));
            h = step_fn(h, xc[3], rc[3], win, wh, c1, c2, c3, wf1, wf2);
            asm volatile("ds_write_b32 %0, %1 offset:768" :: "v"(wa), "v"(h));
            LGKM0;
            __builtin_amdgcn_s_barrier();
        }

        asm volatile("" ::: "memory");  // fence: keep tail mem-ops below region

        // tail steps 1021..1023 + hT (plain; pipeline fully drained)
#pragma unroll
        for (int s = 4 * NG + 1; s < S_LEN; ++s) {
            const float x = inputs[(size_t)s * B_LEN + b];
            const float r = returns[(size_t)(s - 1) * B_LEN + b];
            h = step_fn(h, x, r, win, wh, c1, c2, c3, wf1, wf2);
            out[(size_t)s * B_LEN + b] = h;
        }
        out[(size_t)S_LEN * B_LEN + b] = h;
    } else {
        // ========================= consumer / store wave =====================
        const int j = lane;
        u32x4 ro = make_srsrc(out);
        const uint32_t vo = (uint32_t)((((j >> 4) * B_LEN) + b0 + (j & 15) * 4) * 4);
        const uint32_t outb_a = (uint32_t)(uintptr_t)&outb[0][0][0];
        const uint32_t oa = outb_a + (uint32_t)((j >> 4) * 256 + (j & 15) * 16);

        for (int g = 0; g < NG; ++g) {
            __builtin_amdgcn_s_barrier();          // group g published
            asm volatile("s_waitcnt vmcnt(0)");    // prev store src read out
            __builtin_amdgcn_sched_barrier(0);
            f32x4 o4;
            uint32_t a = oa + (uint32_t)((g & 1) * 1024);
            asm volatile("ds_read_b128 %0, %1" : "=v"(o4) : "v"(a));
            LGKM0;
            uint32_t soS = ((uint32_t)(4 * g + 1)) << 16;  // row 4g+1 base
            asm volatile("buffer_store_dwordx4 %0, %1, %2, %3 offen"
                         :: "v"(o4), "v"(vo), "s"(ro), "s"(soS));
        }
    }
}

extern "C" void kernel_launch(void* const* d_in, const int* in_sizes, int n_in,
                              void* d_out, int out_size, void* d_ws, size_t ws_size,
                              hipStream_t stream) {
    const float* inputs  = (const float*)d_in[0];
    const float* returns = (const float*)d_in[1];
    const float* target  = (const float*)d_in[2];
    const float* w_in    = (const float*)d_in[3];
    const float* w_h     = (const float*)d_in[4];
    const float* b_h     = (const float*)d_in[5];
    const float* w_fc1   = (const float*)d_in[6];
    const float* w_fc2   = (const float*)d_in[7];
    float* out = (float*)d_out;

    dim3 grid(B_LEN / 64);
    dim3 block(128);
    hipLaunchKernelGGL(wealth_rnn_kernel, grid, block, 0, stream,
                       inputs, returns, target, w_in, w_h, b_h, w_fc1, w_fc2, out);
}

// Round 6
// 59.550 us; speedup vs baseline: 1.6671x; 1.0266x over previous
//
#include <hip/hip_runtime.h>
#include <cstdint>

// WealthRNN v6 = v4 (proven-correct) + pipelined wave1 stores ONLY.
//  wave0 (verbatim v4): DMA ring (global_load_lds, D=24 groups, 48 vm ops in
//         flight), counted vmcnt(46)/group; asm ds_read next group; compute 4
//         steps; ds_write outb[g&1]; lgkmcnt(0); s_barrier per group.
//  wave1 (new): 8 rotating f32x4 register sets; per group: s_barrier,
//         vmcnt(7) (retire store issued 8 groups ago), KEEP-ALIVE fake use
//         (closes the dead-register window so regalloc can't recycle a
//         store-source reg while the store is outstanding), ds_read_b128,
//         lgkmcnt(0), buffer_store_dwordx4. No store-completion stalls.

#define S_LEN 1024
#define B_LEN 16384
#define NG    255      // 4-step groups, steps 1..1020
#define D     24       // DMA prefetch depth (groups); wait N = 2D-2 = 46
#define NSLOT 32
#define GSTEP ((size_t)4 * B_LEN)

typedef uint32_t u32x4 __attribute__((ext_vector_type(4)));
typedef float    f32x4 __attribute__((ext_vector_type(4)));

__device__ __forceinline__ u32x4 make_srsrc(const void* p) {
    u32x4 r;
    uint64_t a = (uint64_t)p;
    r.x = (uint32_t)a;
    r.y = (uint32_t)(a >> 32);   // base hi, stride=0
    r.z = 0xFFFFFFFFu;           // bounds check disabled
    r.w = 0x00020000u;           // raw dword descriptor
    return r;
}

#define WAITV(N) do { \
    asm volatile("s_waitcnt vmcnt(%0)" :: "n"(N)); \
    __builtin_amdgcn_sched_barrier(0); } while (0)

#define LGKM0 do { \
    asm volatile("s_waitcnt lgkmcnt(0)"); \
    __builtin_amdgcn_sched_barrier(0); } while (0)

__device__ __forceinline__ void dma16(const float* g, float* l) {
    __builtin_amdgcn_global_load_lds(
        (const __attribute__((address_space(1))) void*)g,
        (__attribute__((address_space(3))) void*)l, 16, 0, 0);
}

// read one group tile (x[0..3], r[0..3]) for this lane's column from slot @ra
#define DSR8(xa, ra_, ca_) do { \
    asm volatile("ds_read_b32 %0, %1 offset:0"    : "=v"(xa[0]) : "v"(ra_)); \
    asm volatile("ds_read_b32 %0, %1 offset:256"  : "=v"(xa[1]) : "v"(ra_)); \
    asm volatile("ds_read_b32 %0, %1 offset:512"  : "=v"(xa[2]) : "v"(ra_)); \
    asm volatile("ds_read_b32 %0, %1 offset:768"  : "=v"(xa[3]) : "v"(ra_)); \
    asm volatile("ds_read_b32 %0, %1 offset:1024" : "=v"(ca_[0]) : "v"(ra_)); \
    asm volatile("ds_read_b32 %0, %1 offset:1280" : "=v"(ca_[1]) : "v"(ra_)); \
    asm volatile("ds_read_b32 %0, %1 offset:1536" : "=v"(ca_[2]) : "v"(ra_)); \
    asm volatile("ds_read_b32 %0, %1 offset:1792" : "=v"(ca_[3]) : "v"(ra_)); \
} while (0)

__device__ __forceinline__ float step_fn(float h, float x, float r,
                                         float win, float wh,
                                         float c1, float c2, float c3,
                                         float wf1, float wf2) {
    float inv   = __builtin_amdgcn_rcpf(fmaf(h, r, 1.0f)); // 1/(1+h*r)
    float h_adj = fmaf(h, r, h) * inv;                      // h*(1+r)/(1+h*r)
    float ingate = fmaf(wh, h_adj, fmaf(x, win, c1));
    float t  = fmaxf(ingate, 0.0f);
    float g2 = fmaf(wf1, t, c2);
    float t2 = fmaxf(g2, 0.0f);
    return fmaf(wf2, t2, c3);
}

// wave1: one group. DOW_=1 -> counted wait + keep-alive before overwrite.
#define WB1(g_, SET, DOW_) do { \
    __builtin_amdgcn_s_barrier(); \
    if (DOW_) { \
        asm volatile("s_waitcnt vmcnt(7)"); \
        __builtin_amdgcn_sched_barrier(0); \
        asm volatile("" :: "v"(SET));   /* keep reg live until store retired */ \
    } \
    { uint32_t a_ = oa + (uint32_t)((((g_) & 1)) * 1024); \
      asm volatile("ds_read_b128 %0, %1" : "=v"(SET) : "v"(a_)); } \
    asm volatile("s_waitcnt lgkmcnt(0)"); \
    __builtin_amdgcn_sched_barrier(0); \
    { uint32_t so_ = ((uint32_t)(4 * (g_) + 1)) << 16; \
      asm volatile("buffer_store_dwordx4 %0, %1, %2, %3 offen" \
                   :: "v"(SET), "v"(vo), "s"(ro), "s"(so_)); } \
} while (0)

__global__ __launch_bounds__(128) void wealth_rnn_kernel(
    const float* __restrict__ inputs,    // [S, B]
    const float* __restrict__ returns,   // [S-1, B]
    const float* __restrict__ target,
    const float* __restrict__ w_in_p,
    const float* __restrict__ w_h_p,
    const float* __restrict__ b_h_p,
    const float* __restrict__ w_fc1_p,
    const float* __restrict__ w_fc2_p,
    float* __restrict__ out)             // [S*B] then [B] hT
{
    __shared__ float ring[NSLOT][2][4][64];   // 64 KiB x/r staging ring
    __shared__ float outb[2][4][64];          // 2 KiB output double buffer

    const int tid  = threadIdx.x;
    const int lane = tid & 63;
    const int wid  = tid >> 6;
    const int b0   = blockIdx.x * 64;

    if (wid == 0) {
        // ============== producer / compute wave (VERBATIM v4) ===============
        const int b = b0 + lane;
        const float pi_bar = target[0];
        const float win = w_in_p[0];
        const float wh  = w_h_p[0];
        const float bh  = b_h_p[0];
        const float wf1 = w_fc1_p[0];
        const float wf2 = w_fc2_p[0];
        const float c1 = bh - pi_bar;
        const float c2 = 2.0f * bh;
        const float c3 = pi_bar + bh;

        float h = inputs[b];
        u32x4 ro = make_srsrc(out);
        const uint32_t voff = (uint32_t)b * 4u;
        const uint32_t so0 = 0u;
        asm volatile("buffer_store_dword %0, %1, %2, %3 offen"
                     :: "v"(h), "v"(voff), "s"(ro), "s"(so0));

        const int lr = lane >> 4;
        const int lc = (lane & 15) * 4;
        const float* gxi = inputs  + (size_t)(1 + lr) * B_LEN + b0 + lc;
        const float* gri = returns + (size_t)lr       * B_LEN + b0 + lc;

        asm volatile("" ::: "memory");  // fence: pin entry mem-ops above region

        // prologue: DMA groups 0..D-1 (2D = 48 vm ops)
#pragma unroll
        for (int j = 0; j < D; ++j) {
            dma16(gxi, &ring[j][0][0][0]);
            dma16(gri, &ring[j][1][0][0]);
            gxi += GSTEP; gri += GSTEP;
        }

        const uint32_t ring_a = (uint32_t)(uintptr_t)&ring[0][0][0][0];
        const uint32_t outb_a = (uint32_t)(uintptr_t)&outb[0][0][0];
        const uint32_t rbase = ring_a + (uint32_t)lane * 4u;
        const uint32_t wbase = outb_a + (uint32_t)lane * 4u;

        float xc[4], rc[4], xn[4], rn[4];

        WAITV(2 * D - 2);            // retire DMA(0) (+ any older entry ops)
        {
            uint32_t ra0 = rbase;    // slot 0
            DSR8(xc, ra0, rc);
        }
        LGKM0;

        // main loop g = 0..230: issue DMA(g+D); wait through DMA(g+1);
        // prefetch slot g+1 LDS->reg; compute group g; publish to wave1.
        for (int g = 0; g < NG - D; ++g) {
            dma16(gxi, &ring[(g + D) & (NSLOT - 1)][0][0][0]);
            dma16(gri, &ring[(g + D) & (NSLOT - 1)][1][0][0]);
            gxi += GSTEP; gri += GSTEP;
            WAITV(2 * D - 2);
            uint32_t ra = rbase + (uint32_t)(((g + 1) & (NSLOT - 1)) * 2048);
            DSR8(xn, ra, rn);
            uint32_t wa = wbase + (uint32_t)((g & 1) * 1024);
            h = step_fn(h, xc[0], rc[0], win, wh, c1, c2, c3, wf1, wf2);
            asm volatile("ds_write_b32 %0, %1 offset:0"   :: "v"(wa), "v"(h));
            h = step_fn(h, xc[1], rc[1], win, wh, c1, c2, c3, wf1, wf2);
            asm volatile("ds_write_b32 %0, %1 offset:256" :: "v"(wa), "v"(h));
            h = step_fn(h, xc[2], rc[2], win, wh, c1, c2, c3, wf1, wf2);
            asm volatile("ds_write_b32 %0, %1 offset:512" :: "v"(wa), "v"(h));
            h = step_fn(h, xc[3], rc[3], win, wh, c1, c2, c3, wf1, wf2);
            asm volatile("ds_write_b32 %0, %1 offset:768" :: "v"(wa), "v"(h));
            LGKM0;                         // xn/rn arrived; out-writes flushed
            __builtin_amdgcn_s_barrier();  // publish group g to wave1
#pragma unroll
            for (int k = 0; k < 4; ++k) { xc[k] = xn[k]; rc[k] = rn[k]; }
        }

        // all DMAs issued (groups 0..254); drain once, then LDS-only tail
        WAITV(0);
        for (int g = NG - D; g < NG - 1; ++g) {   // 231..253
            uint32_t ra = rbase + (uint32_t)(((g + 1) & (NSLOT - 1)) * 2048);
            DSR8(xn, ra, rn);
            uint32_t wa = wbase + (uint32_t)((g & 1) * 1024);
            h = step_fn(h, xc[0], rc[0], win, wh, c1, c2, c3, wf1, wf2);
            asm volatile("ds_write_b32 %0, %1 offset:0"   :: "v"(wa), "v"(h));
            h = step_fn(h, xc[1], rc[1], win, wh, c1, c2, c3, wf1, wf2);
            asm volatile("ds_write_b32 %0, %1 offset:256" :: "v"(wa), "v"(h));
            h = step_fn(h, xc[2], rc[2], win, wh, c1, c2, c3, wf1, wf2);
            asm volatile("ds_write_b32 %0, %1 offset:512" :: "v"(wa), "v"(h));
            h = step_fn(h, xc[3], rc[3], win, wh, c1, c2, c3, wf1, wf2);
            asm volatile("ds_write_b32 %0, %1 offset:768" :: "v"(wa), "v"(h));
            LGKM0;
            __builtin_amdgcn_s_barrier();
#pragma unroll
            for (int k = 0; k < 4; ++k) { xc[k] = xn[k]; rc[k] = rn[k]; }
        }
        {   // final group g = 254 (slot 254&1 = 0), no prefetch
            uint32_t wa = wbase + (uint32_t)(((NG - 1) & 1) * 1024);
            h = step_fn(h, xc[0], rc[0], win, wh, c1, c2, c3, wf1, wf2);
            asm volatile("ds_write_b32 %0, %1 offset:0"   :: "v"(wa), "v"(h));
            h = step_fn(h, xc[1], rc[1], win, wh, c1, c2, c3, wf1, wf2);
            asm volatile("ds_write_b32 %0, %1 offset:256" :: "v"(wa), "v"(h));
            h = step_fn(h, xc[2], rc[2], win, wh, c1, c2, c3, wf1, wf2);
            asm volatile("ds_write_b32 %0, %1 offset:512" :: "v"(wa), "v"(h));
            h = step_fn(h, xc[3], rc[3], win, wh, c1, c2, c3, wf1, wf2);
            asm volatile("ds_write_b32 %0, %1 offset:768" :: "v"(wa), "v"(h));
            LGKM0;
            __builtin_amdgcn_s_barrier();
        }

        asm volatile("" ::: "memory");  // fence: keep tail mem-ops below region

        // tail steps 1021..1023 + hT (plain; pipeline fully drained)
#pragma unroll
        for (int s = 4 * NG + 1; s < S_LEN; ++s) {
            const float x = inputs[(size_t)s * B_LEN + b];
            const float r = returns[(size_t)(s - 1) * B_LEN + b];
            h = step_fn(h, x, r, win, wh, c1, c2, c3, wf1, wf2);
            out[(size_t)s * B_LEN + b] = h;
        }
        out[(size_t)S_LEN * B_LEN + b] = h;
    } else {
        // ============== consumer / store wave (pipelined, new) ==============
        const int j = lane;
        u32x4 ro = make_srsrc(out);
        const uint32_t vo = (uint32_t)((((j >> 4) * B_LEN) + b0 + (j & 15) * 4) * 4);
        const uint32_t outb_a = (uint32_t)(uintptr_t)&outb[0][0][0];
        const uint32_t oa = outb_a + (uint32_t)((j >> 4) * 256 + (j & 15) * 16);

        f32x4 o0, o1, o2, o3, o4, o5, o6, o7;

        // block 0: groups 0..7, registers fresh -> no waits
        WB1(0, o0, 0); WB1(1, o1, 0); WB1(2, o2, 0); WB1(3, o3, 0);
        WB1(4, o4, 0); WB1(5, o5, 0); WB1(6, o6, 0); WB1(7, o7, 0);

        // blocks 1..30: groups 8..247
        for (int blk = 1; blk < 31; ++blk) {
            const int g8 = blk * 8;
            WB1(g8 + 0, o0, 1); WB1(g8 + 1, o1, 1);
            WB1(g8 + 2, o2, 1); WB1(g8 + 3, o3, 1);
            WB1(g8 + 4, o4, 1); WB1(g8 + 5, o5, 1);
            WB1(g8 + 6, o6, 1); WB1(g8 + 7, o7, 1);
        }

        // tail: groups 248..254
        WB1(248, o0, 1); WB1(249, o1, 1); WB1(250, o2, 1); WB1(251, o3, 1);
        WB1(252, o4, 1); WB1(253, o5, 1); WB1(254, o6, 1);
    }
}

extern "C" void kernel_launch(void* const* d_in, const int* in_sizes, int n_in,
                              void* d_out, int out_size, void* d_ws, size_t ws_size,
                              hipStream_t stream) {
    const float* inputs  = (const float*)d_in[0];
    const float* returns = (const float*)d_in[1];
    const float* target  = (const float*)d_in[2];
    const float* w_in    = (const float*)d_in[3];
    const float* w_h     = (const float*)d_in[4];
    const float* b_h     = (const float*)d_in[5];
    const float* w_fc1   = (const float*)d_in[6];
    const float* w_fc2   = (const float*)d_in[7];
    float* out = (float*)d_out;

    dim3 grid(B_LEN / 64);
    dim3 block(128);
    hipLaunchKernelGGL(wealth_rnn_kernel, grid, block, 0, stream,
                       inputs, returns, target, w_in, w_h, b_h, w_fc1, w_fc2, out);
}

// Round 7
// 58.270 us; speedup vs baseline: 1.7037x; 1.0220x over previous
//
#include <hip/hip_runtime.h>
#include <cstdint>

// WealthRNN v7 = v6 + batched publish (4 groups/barrier) ONLY.
//  wave0: DMA ring (global_load_lds, D=24 groups, 48 vm ops in flight),
//         counted vmcnt(46)/group; asm ds_read next group; compute 4 steps;
//         ds_write outb[g&7]; per-group counted lgkmcnt(4) (retires next
//         group's reads, lets current writes float); lgkmcnt(0)+s_barrier
//         only at batch ends (g%4==3) and after final group.
//  wave1: per 4-group batch: s_barrier, vmcnt(4) (2-batch store pipeline),
//         keep-alive fence (regalloc can't recycle store-src regs while the
//         store is outstanding), 4x ds_read_b128, lgkmcnt(0), 4x
//         buffer_store_dwordx4. 63 full batches + 1 partial (3 groups).

#define S_LEN 1024
#define B_LEN 16384
#define NG    255      // 4-step groups, steps 1..1020
#define D     24       // DMA prefetch depth (groups); wait N = 2D-2 = 46
#define NSLOT 32
#define GSTEP ((size_t)4 * B_LEN)

typedef uint32_t u32x4 __attribute__((ext_vector_type(4)));
typedef float    f32x4 __attribute__((ext_vector_type(4)));

__device__ __forceinline__ u32x4 make_srsrc(const void* p) {
    u32x4 r;
    uint64_t a = (uint64_t)p;
    r.x = (uint32_t)a;
    r.y = (uint32_t)(a >> 32);   // base hi, stride=0
    r.z = 0xFFFFFFFFu;           // bounds check disabled
    r.w = 0x00020000u;           // raw dword descriptor
    return r;
}

#define SBAR0 __builtin_amdgcn_sched_barrier(0)

#define WAITV(N) do { \
    asm volatile("s_waitcnt vmcnt(%0)" :: "n"(N)); \
    SBAR0; } while (0)

#define LGKM0 do { \
    asm volatile("s_waitcnt lgkmcnt(0)"); \
    SBAR0; } while (0)

#define LGKM4 do { \
    asm volatile("s_waitcnt lgkmcnt(4)"); \
    SBAR0; } while (0)

__device__ __forceinline__ void dma16(const float* g, float* l) {
    __builtin_amdgcn_global_load_lds(
        (const __attribute__((address_space(1))) void*)g,
        (__attribute__((address_space(3))) void*)l, 16, 0, 0);
}

// read one group tile (x[0..3], r[0..3]) for this lane's column from slot @ra
#define DSR8(xa, ra_, ca_) do { \
    asm volatile("ds_read_b32 %0, %1 offset:0"    : "=v"(xa[0]) : "v"(ra_)); \
    asm volatile("ds_read_b32 %0, %1 offset:256"  : "=v"(xa[1]) : "v"(ra_)); \
    asm volatile("ds_read_b32 %0, %1 offset:512"  : "=v"(xa[2]) : "v"(ra_)); \
    asm volatile("ds_read_b32 %0, %1 offset:768"  : "=v"(xa[3]) : "v"(ra_)); \
    asm volatile("ds_read_b32 %0, %1 offset:1024" : "=v"(ca_[0]) : "v"(ra_)); \
    asm volatile("ds_read_b32 %0, %1 offset:1280" : "=v"(ca_[1]) : "v"(ra_)); \
    asm volatile("ds_read_b32 %0, %1 offset:1536" : "=v"(ca_[2]) : "v"(ra_)); \
    asm volatile("ds_read_b32 %0, %1 offset:1792" : "=v"(ca_[3]) : "v"(ra_)); \
} while (0)

__device__ __forceinline__ float step_fn(float h, float x, float r,
                                         float win, float wh,
                                         float c1, float c2, float c3,
                                         float wf1, float wf2) {
    float inv   = __builtin_amdgcn_rcpf(fmaf(h, r, 1.0f)); // 1/(1+h*r)
    float h_adj = fmaf(h, r, h) * inv;                      // h*(1+r)/(1+h*r)
    float ingate = fmaf(wh, h_adj, fmaf(x, win, c1));
    float t  = fmaxf(ingate, 0.0f);
    float g2 = fmaf(wf1, t, c2);
    float t2 = fmaxf(g2, 0.0f);
    return fmaf(wf2, t2, c3);
}

// compute 4 steps of group g_, write to outb slot g_&7
#define COMPUTE4(CX, CR, g_) do { \
    uint32_t wa_ = wbase + (uint32_t)(((g_) & 7) * 1024); \
    h = step_fn(h, CX[0], CR[0], win, wh, c1, c2, c3, wf1, wf2); \
    asm volatile("ds_write_b32 %0, %1 offset:0"   :: "v"(wa_), "v"(h)); \
    h = step_fn(h, CX[1], CR[1], win, wh, c1, c2, c3, wf1, wf2); \
    asm volatile("ds_write_b32 %0, %1 offset:256" :: "v"(wa_), "v"(h)); \
    h = step_fn(h, CX[2], CR[2], win, wh, c1, c2, c3, wf1, wf2); \
    asm volatile("ds_write_b32 %0, %1 offset:512" :: "v"(wa_), "v"(h)); \
    h = step_fn(h, CX[3], CR[3], win, wh, c1, c2, c3, wf1, wf2); \
    asm volatile("ds_write_b32 %0, %1 offset:768" :: "v"(wa_), "v"(h)); \
} while (0)

// wave1: one 4-group batch. Slots 4*(bt&1)..+3 at LDS half HOFF_.
#define WB4(bt_, HOFF_, P0, P1, P2, P3) do { \
    __builtin_amdgcn_s_barrier(); \
    asm volatile("s_waitcnt vmcnt(4)"); \
    SBAR0; \
    asm volatile("" :: "v"(P0), "v"(P1), "v"(P2), "v"(P3)); /* keep-alive */ \
    { uint32_t a_ = oa + (HOFF_); \
      asm volatile("ds_read_b128 %0, %1 offset:0"    : "=v"(P0) : "v"(a_)); \
      asm volatile("ds_read_b128 %0, %1 offset:1024" : "=v"(P1) : "v"(a_)); \
      asm volatile("ds_read_b128 %0, %1 offset:2048" : "=v"(P2) : "v"(a_)); \
      asm volatile("ds_read_b128 %0, %1 offset:3072" : "=v"(P3) : "v"(a_)); } \
    asm volatile("s_waitcnt lgkmcnt(0)"); \
    SBAR0; \
    { uint32_t so_ = ((uint32_t)(16 * (bt_) + 1)) << 16; \
      asm volatile("buffer_store_dwordx4 %0, %1, %2, %3 offen" \
                   :: "v"(P0), "v"(vo), "s"(ro), "s"(so_)); \
      so_ += (4u << 16); \
      asm volatile("buffer_store_dwordx4 %0, %1, %2, %3 offen" \
                   :: "v"(P1), "v"(vo), "s"(ro), "s"(so_)); \
      so_ += (4u << 16); \
      asm volatile("buffer_store_dwordx4 %0, %1, %2, %3 offen" \
                   :: "v"(P2), "v"(vo), "s"(ro), "s"(so_)); \
      so_ += (4u << 16); \
      asm volatile("buffer_store_dwordx4 %0, %1, %2, %3 offen" \
                   :: "v"(P3), "v"(vo), "s"(ro), "s"(so_)); } \
} while (0)

__global__ __launch_bounds__(128) void wealth_rnn_kernel(
    const float* __restrict__ inputs,    // [S, B]
    const float* __restrict__ returns,   // [S-1, B]
    const float* __restrict__ target,
    const float* __restrict__ w_in_p,
    const float* __restrict__ w_h_p,
    const float* __restrict__ b_h_p,
    const float* __restrict__ w_fc1_p,
    const float* __restrict__ w_fc2_p,
    float* __restrict__ out)             // [S*B] then [B] hT
{
    __shared__ float ring[NSLOT][2][4][64];   // 64 KiB x/r staging ring
    __shared__ float outb[8][4][64];          // 8 KiB output slots (8 groups)

    const int tid  = threadIdx.x;
    const int lane = tid & 63;
    const int wid  = tid >> 6;
    const int b0   = blockIdx.x * 64;

    if (wid == 0) {
        // ===================== producer / compute wave ======================
        const int b = b0 + lane;
        const float pi_bar = target[0];
        const float win = w_in_p[0];
        const float wh  = w_h_p[0];
        const float bh  = b_h_p[0];
        const float wf1 = w_fc1_p[0];
        const float wf2 = w_fc2_p[0];
        const float c1 = bh - pi_bar;
        const float c2 = 2.0f * bh;
        const float c3 = pi_bar + bh;

        float h = inputs[b];
        u32x4 ro = make_srsrc(out);
        const uint32_t voff = (uint32_t)b * 4u;
        const uint32_t so0 = 0u;
        asm volatile("buffer_store_dword %0, %1, %2, %3 offen"
                     :: "v"(h), "v"(voff), "s"(ro), "s"(so0));

        const int lr = lane >> 4;
        const int lc = (lane & 15) * 4;
        const float* gxi = inputs  + (size_t)(1 + lr) * B_LEN + b0 + lc;
        const float* gri = returns + (size_t)lr       * B_LEN + b0 + lc;

        asm volatile("" ::: "memory");  // fence: pin entry mem-ops above region

        // prologue: DMA groups 0..D-1 (2D = 48 vm ops)
#pragma unroll
        for (int j = 0; j < D; ++j) {
            dma16(gxi, &ring[j][0][0][0]);
            dma16(gri, &ring[j][1][0][0]);
            gxi += GSTEP; gri += GSTEP;
        }

        const uint32_t ring_a = (uint32_t)(uintptr_t)&ring[0][0][0][0];
        const uint32_t outb_a = (uint32_t)(uintptr_t)&outb[0][0][0];
        const uint32_t rbase = ring_a + (uint32_t)lane * 4u;
        const uint32_t wbase = outb_a + (uint32_t)lane * 4u;

        float xc[4], rc[4], xn[4], rn[4];

        WAITV(2 * D - 2);            // retire DMA(0) (+ any older entry ops)
        {
            uint32_t ra0 = rbase;    // slot 0
            DSR8(xc, ra0, rc);
        }
        LGKM0;

        // main loop g = 0..230: issue DMA(g+D); wait through DMA(g+1);
        // prefetch slot g+1 LDS->reg; compute group g; publish every 4th.
        for (int g = 0; g < NG - D; ++g) {
            dma16(gxi, &ring[(g + D) & (NSLOT - 1)][0][0][0]);
            dma16(gri, &ring[(g + D) & (NSLOT - 1)][1][0][0]);
            gxi += GSTEP; gri += GSTEP;
            WAITV(2 * D - 2);
            uint32_t ra = rbase + (uint32_t)(((g + 1) & (NSLOT - 1)) * 2048);
            DSR8(xn, ra, rn);
            COMPUTE4(xc, rc, g);
            if ((g & 3) == 3) {          // batch end: drain writes, publish
                LGKM0;
                __builtin_amdgcn_s_barrier();
            } else {                     // retire next-group reads only
                LGKM4;
            }
#pragma unroll
            for (int k = 0; k < 4; ++k) { xc[k] = xn[k]; rc[k] = rn[k]; }
        }

        // all DMAs issued (groups 0..254); drain once, then LDS-only groups
        WAITV(0);
        for (int g = NG - D; g < NG - 1; ++g) {   // 231..253
            uint32_t ra = rbase + (uint32_t)(((g + 1) & (NSLOT - 1)) * 2048);
            DSR8(xn, ra, rn);
            COMPUTE4(xc, rc, g);
            if ((g & 3) == 3) {
                LGKM0;
                __builtin_amdgcn_s_barrier();
            } else {
                LGKM4;
            }
#pragma unroll
            for (int k = 0; k < 4; ++k) { xc[k] = xn[k]; rc[k] = rn[k]; }
        }
        {   // final group g = 254 (slot 6), no prefetch; final publish
            COMPUTE4(xc, rc, NG - 1);
            LGKM0;
            __builtin_amdgcn_s_barrier();
        }

        asm volatile("" ::: "memory");  // fence: keep tail mem-ops below region

        // tail steps 1021..1023 + hT (plain; pipeline fully drained)
#pragma unroll
        for (int s = 4 * NG + 1; s < S_LEN; ++s) {
            const float x = inputs[(size_t)s * B_LEN + b];
            const float r = returns[(size_t)(s - 1) * B_LEN + b];
            h = step_fn(h, x, r, win, wh, c1, c2, c3, wf1, wf2);
            out[(size_t)s * B_LEN + b] = h;
        }
        out[(size_t)S_LEN * B_LEN + b] = h;
    } else {
        // ============== consumer / store wave (batch-4 pipelined) ===========
        const int j = lane;
        u32x4 ro = make_srsrc(out);
        const uint32_t vo = (uint32_t)((((j >> 4) * B_LEN) + b0 + (j & 15) * 4) * 4);
        const uint32_t outb_a = (uint32_t)(uintptr_t)&outb[0][0][0];
        const uint32_t oa = outb_a + (uint32_t)((j >> 4) * 256 + (j & 15) * 16);

        f32x4 o0 = {0,0,0,0}, o1 = {0,0,0,0}, o2 = {0,0,0,0}, o3 = {0,0,0,0};
        f32x4 o4 = {0,0,0,0}, o5 = {0,0,0,0}, o6 = {0,0,0,0}, o7 = {0,0,0,0};

        // full batches bt = 0..62 (groups 0..251)
        for (int bt2 = 0; bt2 < 31; ++bt2) {
            WB4(2 * bt2,     0,    o0, o1, o2, o3);
            WB4(2 * bt2 + 1, 4096, o4, o5, o6, o7);
        }
        WB4(62, 0, o0, o1, o2, o3);

        // final partial batch: groups 252..254 (slots 4,5,6), rows 1009..1020
        __builtin_amdgcn_s_barrier();
        asm volatile("s_waitcnt vmcnt(4)");
        SBAR0;
        asm volatile("" :: "v"(o4), "v"(o5), "v"(o6));   // keep-alive
        {
            uint32_t a_ = oa + 4096;
            asm volatile("ds_read_b128 %0, %1 offset:0"    : "=v"(o4) : "v"(a_));
            asm volatile("ds_read_b128 %0, %1 offset:1024" : "=v"(o5) : "v"(a_));
            asm volatile("ds_read_b128 %0, %1 offset:2048" : "=v"(o6) : "v"(a_));
        }
        asm volatile("s_waitcnt lgkmcnt(0)");
        SBAR0;
        {
            uint32_t so_ = ((uint32_t)(4 * 252 + 1)) << 16;
            asm volatile("buffer_store_dwordx4 %0, %1, %2, %3 offen"
                         :: "v"(o4), "v"(vo), "s"(ro), "s"(so_));
            so_ += (4u << 16);
            asm volatile("buffer_store_dwordx4 %0, %1, %2, %3 offen"
                         :: "v"(o5), "v"(vo), "s"(ro), "s"(so_));
            so_ += (4u << 16);
            asm volatile("buffer_store_dwordx4 %0, %1, %2, %3 offen"
                         :: "v"(o6), "v"(vo), "s"(ro), "s"(so_));
        }
    }
}

extern "C" void kernel_launch(void* const* d_in, const int* in_sizes, int n_in,
                              void* d_out, int out_size, void* d_ws, size_t ws_size,
                              hipStream_t stream) {
    const float* inputs  = (const float*)d_in[0];
    const float* returns = (const float*)d_in[1];
    const float* target  = (const float*)d_in[2];
    const float* w_in    = (const float*)d_in[3];
    const float* w_h     = (const float*)d_in[4];
    const float* b_h     = (const float*)d_in[5];
    const float* w_fc1   = (const float*)d_in[6];
    const float* w_fc2   = (const float*)d_in[7];
    float* out = (float*)d_out;

    dim3 grid(B_LEN / 64);
    dim3 block(128);
    hipLaunchKernelGGL(wealth_rnn_kernel, grid, block, 0, stream,
                       inputs, returns, target, w_in, w_h, b_h, w_fc1, w_fc2, out);
}